// Round 1
// baseline (194.916 us; speedup 1.0000x reference)
//
#include <hip/hip_runtime.h>

// QNN closed form: q_b = prod_{i<8} cos(pi/2 + 2*x_bi) = prod_{i<8} sin(2*x_bi)
// (8 negative signs cancel). out[b,0] = s*q, out[b,1] = -s*q.
//
// Coalescing scheme: global thread t loads float4 #t of x (two threads per row),
// forms a 4-factor partial product, exchanges with partner lane (t^1) via
// __shfl_xor to get the full 8-factor product, and writes out[t]
// (= out[row=t>>1][col=t&1]). Loads are 16B/lane contiguous, stores 4B/lane
// contiguous — both perfectly coalesced, no LDS needed.

__global__ __launch_bounds__(256) void qnn_kernel(const float4* __restrict__ x4,
                                                  const float* __restrict__ scale_p,
                                                  float* __restrict__ out,
                                                  int n4) {
    int t = blockIdx.x * blockDim.x + threadIdx.x;
    if (t >= n4) return;

    float4 v = x4[t];
    // __sinf: v_mul (1/2pi) + v_sin_f32. |2x| <~ 12 rad for N(0,1) inputs -> accurate.
    float p = __sinf(2.0f * v.x) * __sinf(2.0f * v.y) *
              __sinf(2.0f * v.z) * __sinf(2.0f * v.w);

    float q = p * __shfl_xor(p, 1, 64);   // full 8-factor row product

    float s = scale_p[0];
    out[t] = (t & 1) ? (-s * q) : (s * q);
}

extern "C" void kernel_launch(void* const* d_in, const int* in_sizes, int n_in,
                              void* d_out, int out_size, void* d_ws, size_t ws_size,
                              hipStream_t stream) {
    const float4* x4    = (const float4*)d_in[0];   // [B,8] fp32 viewed as [B*2] float4
    const float*  scale = (const float*)d_in[2];    // scalar (d_in[1] = weights, unused)
    float*        out   = (float*)d_out;            // [B,2] fp32 flat = B*2 floats

    int n4 = in_sizes[0] / 4;                       // B*2 float4 chunks == out elements
    int block = 256;
    int grid = (n4 + block - 1) / block;
    qnn_kernel<<<grid, block, 0, stream>>>(x4, scale, out, n4);
}